// Round 8
// baseline (371.427 us; speedup 1.0000x reference)
//
#include <hip/hip_runtime.h>

#define PLANE 65536
#define WIDTH 256
#define PADW 258
#define PADPLANE 66564   // 258*258

typedef __bf16 v8bf __attribute__((ext_vector_type(8)));
typedef float  v4f  __attribute__((ext_vector_type(4)));

typedef const __attribute__((address_space(1))) unsigned int* gas_ptr;
typedef __attribute__((address_space(3))) unsigned int* las_ptr;

// async global->LDS, 16 B per lane; LDS dest = wave-uniform base + lane*16
__device__ __forceinline__ void gl_lds(const void* g, void* l) {
  __builtin_amdgcn_global_load_lds((gas_ptr)g, (las_ptr)l, 16, 0, 0);
}

// self-inverse 16B-chunk swizzle within 8-chunk groups
__device__ __forceinline__ int swz(int c) {
  return (c & ~7) | ((c & 7) ^ ((c >> 3) & 7));
}

__device__ __forceinline__ int m6(int x) { return x >= 6 ? x - 6 : x; }

__device__ __forceinline__ unsigned int pack2(float a, float b) {
  __bf16 ba = (__bf16)a, bb = (__bf16)b;
  unsigned short sa = __builtin_bit_cast(unsigned short, ba);
  unsigned short sb = __builtin_bit_cast(unsigned short, bb);
  return (unsigned int)sa | ((unsigned int)sb << 16);
}

// ---------------------------------------------------------------------------
// wz_k: fused weight-prep + padding-ring zeroing (act1 + act3 only).
// ---------------------------------------------------------------------------
#define WT_N 37440                       // 288+18432+18432+288
#define ZR_N (8 * 1028 * 32)             // 16+16 uints per ring px
__global__ __launch_bounds__(256) void wz_k(
    const float* __restrict__ w1, const float* __restrict__ w2,
    const float* __restrict__ w3, const float* __restrict__ w4,
    float* __restrict__ w1t, __bf16* __restrict__ B2t,
    __bf16* __restrict__ B3t, float* __restrict__ w4t,
    __bf16* __restrict__ a1, __bf16* __restrict__ a3)
{
  int t = blockIdx.x * 256 + threadIdx.x;
  if (t < WT_N) {
    if (t < 288) {                       // w1: [32][1][9] -> [tap][32]
      int tap = t >> 5, cout = t & 31;
      w1t[t] = w1[cout * 9 + tap];
    }
    int t2 = t - 288;
    if (t2 >= 0 && t2 < 18432) {         // 64 x 288
      int cout = t2 / 288, k = t2 % 288;
      int tap = k / 32, cin = k % 32;
      B2t[t2] = (__bf16)w2[cout * 288 + cin * 9 + tap];
    }
    int t3 = t - (288 + 18432);
    if (t3 >= 0 && t3 < 18432) {         // 32 x 576
      int cout = t3 / 576, k = t3 % 576;
      int tap = k / 64, cin = k % 64;
      B3t[t3] = (__bf16)w3[cout * 576 + cin * 9 + tap];
    }
    int t4 = t - (288 + 18432 + 18432);
    if (t4 >= 0 && t4 < 288) {           // w4: [1][32][9] -> [tap][32]
      int tap = t4 >> 5, cin = t4 & 31;
      w4t[t4] = w4[cin * 9 + tap];
    }
    return;
  }
  int idx = t - WT_N;
  if (idx >= ZR_N) return;
  unsigned int* p;
  const int R1 = 8 * 1028 * 16;
  if (idx < R1) p = (unsigned int*)a1;
  else         { p = (unsigned int*)a3; idx -= R1; }
  int ch = idx & 15;
  int pr = idx >> 4;                 // 0 .. 8*1028-1
  int b = pr / 1028, r = pr % 1028;
  int y, x;
  if      (r < 258) { y = 0;           x = r; }
  else if (r < 516) { y = 257;         x = r - 258; }
  else if (r < 772) { y = r - 516 + 1; x = 0; }
  else              { y = r - 772 + 1; x = 257; }
  p[((size_t)b * PADPLANE + y * PADW + x) * 16 + ch] = 0;
}

// ---------------------------------------------------------------------------
// prepconv1_k: fused prep + conv1 (unchanged).
// ---------------------------------------------------------------------------
__global__ __launch_bounds__(256) void prepconv1_k(
    const float* __restrict__ inputs, const float* __restrict__ H0,
    const float* __restrict__ C0, const float* __restrict__ c2p,
    const float* __restrict__ sfp, const float* __restrict__ w1t,
    const float* __restrict__ b1, float* __restrict__ dout,
    __bf16* __restrict__ act1)
{
  const int x = threadIdx.x, y = blockIdx.x, b = blockIdx.y;
  const int p = b * PLANE + y * WIDTH + x;
  const float c2 = c2p[0], sf = sfp[0], rsf = 1.0f / sf;

  float iv[3][3], hv[3][3];
  #pragma unroll
  for (int dy = 0; dy < 3; dy++) {
    int yy = y + dy - 1;
    #pragma unroll
    for (int dx = 0; dx < 3; dx++) {
      int xx = x + dx - 1;
      bool ok = (yy >= 0 && yy < 256 && xx >= 0 && xx < 256);
      int pn = p + (dy - 1) * WIDTH + (dx - 1);
      iv[dy][dx] = ok ? inputs[pn] : 0.f;
      hv[dy][dx] = ok ? H0[pn]     : 0.f;
    }
  }
  const float in = iv[1][1], h0 = hv[1][1];
  const float c0a = C0[b * 131072 + y * WIDTH + x];
  float lap = iv[0][1] + iv[2][1] + iv[1][0] + iv[1][2] - 4.f * in;
  float Hv = 2.f * in - c0a + c2 * lap;
  float V  = in - h0;
  dout[524288 + p]  = Hv;                               // H
  dout[2097152 + p] = V;                                // V
  dout[1048576 + b * 131072 + y * WIDTH + x]         = in;   // C_new[:,0]
  dout[1048576 + b * 131072 + 65536 + y * WIDTH + x] = c0a;  // C_new[:,1]

  float acc[32];
  #pragma unroll
  for (int i = 0; i < 32; i++) acc[i] = b1[i];
  #pragma unroll
  for (int tap = 0; tap < 9; tap++) {
    float v = (iv[tap / 3][tap % 3] - hv[tap / 3][tap % 3]) * rsf;
    const float* wp = w1t + tap * 32;                   // uniform
    #pragma unroll
    for (int i = 0; i < 32; i++) acc[i] = fmaf(wp[i], v, acc[i]);
  }
  unsigned int u[16];
  #pragma unroll
  for (int j = 0; j < 16; j++)
    u[j] = pack2(fmaxf(acc[2*j], 0.f), fmaxf(acc[2*j+1], 0.f));
  size_t pa = ((size_t)b * PADPLANE + (y+1) * PADW + (x+1)) * 32;
  uint4* op = reinterpret_cast<uint4*>(act1 + pa);
  #pragma unroll
  for (int j = 0; j < 4; j++)
    op[j] = make_uint4(u[4*j], u[4*j+1], u[4*j+2], u[4*j+3]);
}

// ---------------------------------------------------------------------------
// conv23_k: FUSED conv2+conv3, producer/consumer wave specialization.
//
// ROUND-8: r7 showed 2.5x latency slack (no pipe >40%, 4 waves/SIMD).
// x-tile 64 -> 32: LDS/block = 6*4352 + 6*2304 + 1024 = 40960 B
// = EXACTLY 160KiB/4 -> 4 blocks/CU, 8 waves/SIMD (2048 thr = CU max).
// ~+11% instructions (ragged 3rd m-tile), 2x TLP. Numerics bit-identical
// (per-output tap order preserved; ragged tiles write-masked).
// a1 index j <-> padded x0-1+j (j=0..35); a2 index i <-> padded x0+i
// (i=0..33); consumer output px 0..31 <-> padded x0+1+px.
// ---------------------------------------------------------------------------
#define A1ROWB 2304   // 36 px * 32 ch * 2 B = 144 chunks
#define A2ROWB 4352   // 34 px * 64 ch * 2 B = 272 chunks
__global__ __launch_bounds__(512, 8) void conv23_k(
    const __bf16* __restrict__ act1, const __bf16* __restrict__ B2t,
    const float* __restrict__ b2, const __bf16* __restrict__ B3t,
    const float* __restrict__ b3, __bf16* __restrict__ act3)
{
  const int lane = threadIdx.x & 63, wave = threadIdx.x >> 6;
  const int l15 = lane & 15, q = lane >> 4;
  const int y0 = blockIdx.x * 16, xt = blockIdx.y, b = blockIdx.z;
  const int x0 = xt * 32;
  __shared__ __align__(16) char smem[6 * A2ROWB + 6 * A1ROWB + 1024];
  char* a2r = smem;                       // act2 ring (6 slots)
  char* a1r = smem + 6 * A2ROWB;          // act1 ring (6 slots; +1KB pad for
                                          //  ragged m-tile over-reads)
  const __bf16* plane = act1 + (size_t)b * PADPLANE * 32;

  if (wave < 4) {
    // ------------------------- PRODUCER (conv2) -------------------------
    auto stageA1 = [&](int k, int slot) {  // a1 rel row k = padded y0-1+k
      int a = y0 - 1 + k;
      a = a < 0 ? 0 : (a > 257 ? 257 : a);
      // 144 chunks/row, 36 per wave (exec-masked gl_lds)
      const char* g = (const char*)(plane + ((size_t)a * PADW + x0 - 1) * 32);
      char* lrow = a1r + slot * A1ROWB;
      const int base = wave * 36;
      if (lane < 36)
        gl_lds(g + (size_t)swz(base + lane) * 16, lrow + base * 16);
    };

    v8bf breg2[9];                         // this wave's 16 couts
    #pragma unroll
    for (int tap = 0; tap < 9; tap++)
      breg2[tap] = *(const v8bf*)(B2t + (size_t)(wave * 16 + l15) * 288
                                      + tap * 32 + q * 8);
    const v4f bv2 = *(const v4f*)(b2 + wave * 16 + q * 4);

    auto zrow = [&](int sl) {              // zero a2 ring slot (272 chunks)
      char* drow = a2r + sl * A2ROWB;
      int c = threadIdx.x;                 // P-group: 0..255
      *(uint4*)(drow + (size_t)c * 16) = make_uint4(0,0,0,0);
      if (c < 16)
        *(uint4*)(drow + (size_t)(c + 256) * 16) = make_uint4(0,0,0,0);
    };

    // produce a2 rel rows t and t+1 (slots s, s+1); each a1 row read ONCE
    auto producePair = [&](int t, int s) {
      const int s1 = m6(s + 1);
      const bool z0 = (y0 + t == 0) || (y0 + t == 257);
      const bool z1 = (y0 + t + 1 == 0) || (y0 + t + 1 == 257);
      if (z0) zrow(s);
      if (z1) zrow(s1);
      if (z0 && z1) return;
      v4f acc0[3], acc1v[3];
      #pragma unroll
      for (int m = 0; m < 3; m++) { acc0[m] = bv2; acc1v[m] = bv2; }
      #pragma unroll
      for (int r = 0; r < 4; r++) {        // a1 rel row t+r (dy=r for row t)
        if (z0 && r == 0) continue;        // r0 feeds only row t
        if (z1 && r == 3) continue;        // r3 feeds only row t+1
        const char* srow = a1r + m6(s + r) * A1ROWB;
        #pragma unroll
        for (int dx = 0; dx < 3; dx++) {
          #pragma unroll
          for (int m = 0; m < 3; m++) {
            int j = m * 16 + l15 + dx;     // >35 over-reads: garbage, unused
            v8bf af = *(const v8bf*)(srow + (size_t)swz(j * 4 + q) * 16);
            if (!z0 && r <= 2)             // row t, tap (dy=r, dx)
              acc0[m] = __builtin_amdgcn_mfma_f32_16x16x32_bf16(
                  breg2[r * 3 + dx], af, acc0[m], 0, 0, 0);
            if (!z1 && r >= 1)             // row t+1, tap (dy=r-1, dx)
              acc1v[m] = __builtin_amdgcn_mfma_f32_16x16x32_bf16(
                  breg2[(r - 1) * 3 + dx], af, acc1v[m], 0, 0, 0);
          }
        }
      }
      const int c = wave * 2 + (q >> 1), boff = (q & 1) * 8;
      #pragma unroll
      for (int rr = 0; rr < 2; rr++) {
        if (rr == 0 && z0) continue;
        if (rr == 1 && z1) continue;
        char* drow = a2r + (rr ? s1 : s) * A2ROWB;
        v4f* A = rr ? acc1v : acc0;
        #pragma unroll
        for (int m = 0; m < 3; m++) {
          int px = m * 16 + l15;
          bool w = (m < 2) || (l15 < 2);               // px <= 33
          if (x0 == 0   && px == 0)  w = false;        // x-halo -> zeroed
          if (x0 == 224 && px == 33) w = false;
          if (w) {
            unsigned int lo = pack2(fmaxf(A[m][0], 0.f), fmaxf(A[m][1], 0.f));
            unsigned int hi = pack2(fmaxf(A[m][2], 0.f), fmaxf(A[m][3], 0.f));
            *(uint2*)(drow + (size_t)swz(px * 8 + c) * 16 + boff)
                = make_uint2(lo, hi);
          }
        }
        if (x0 == 0 && threadIdx.x < 8)            // zero px slot 0 (halo)
          *(uint4*)(drow + (size_t)swz(threadIdx.x) * 16) = make_uint4(0,0,0,0);
        if (x0 == 224 && threadIdx.x < 8)          // zero px slot 33 (halo)
          *(uint4*)(drow + (size_t)swz(264 + threadIdx.x) * 16) = make_uint4(0,0,0,0);
      }
    };

    // prologue: a1 rows 0..5; produce a2 rows 0..3; a1 rows 6,7
    #pragma unroll
    for (int k = 0; k < 6; k++) stageA1(k, k);
    asm volatile("s_waitcnt vmcnt(0)" ::: "memory");
    __builtin_amdgcn_s_barrier();                         // bar 1
    __builtin_amdgcn_sched_barrier(0);
    producePair(0, 0); producePair(2, 2);
    asm volatile("s_waitcnt lgkmcnt(0)" ::: "memory");
    __builtin_amdgcn_s_barrier();                         // bar 2
    __builtin_amdgcn_sched_barrier(0);
    stageA1(6, 0); stageA1(7, 1);
    asm volatile("s_waitcnt vmcnt(0)" ::: "memory");
    __builtin_amdgcn_s_barrier();                         // bar 3
    __builtin_amdgcn_sched_barrier(0);

    int sb = 2;                                           // (2ps+2)%6
    for (int ps = 0; ps < 8; ps++) {
      // stage a1 rows 2ps+8,9 (clamped; land in just-freed slots)
      int r0 = 2 * ps + 8, r1 = 2 * ps + 9;
      stageA1(r0 > 19 ? 19 : r0, sb);
      stageA1(r1 > 19 ? 19 : r1, m6(sb + 1));
      // produce a2 rows 2ps+4,5 (a1 rows 2ps+4..2ps+7 staged+drained)
      if (2 * ps + 4 <= 17) producePair(2 * ps + 4, m6(sb + 2));
      // own-wave drains BEFORE the shared barrier (cross-wave visibility)
      asm volatile("s_waitcnt vmcnt(0) lgkmcnt(0)" ::: "memory");
      __builtin_amdgcn_s_barrier();                       // bar 4+ps
      __builtin_amdgcn_sched_barrier(0);
      sb = m6(sb + 2);
    }
  } else {
    // ------------------------- CONSUMER (conv3) -------------------------
    const int cw = wave - 4;
    const int Mh = cw >> 1, ntw = cw & 1;  // px 16-tile, cout half
    v8bf breg3[9][2];                          // tap, kb
    #pragma unroll
    for (int tap = 0; tap < 9; tap++)
      #pragma unroll
      for (int kb = 0; kb < 2; kb++)
        breg3[tap][kb] = *(const v8bf*)(B3t + (size_t)(ntw * 16 + l15) * 576
                                            + tap * 64 + kb * 32 + q * 8);
    const float bv3 = b3[ntw * 16 + l15];

    __builtin_amdgcn_s_barrier();                         // bar 1
    __builtin_amdgcn_s_barrier();                         // bar 2
    __builtin_amdgcn_s_barrier();                         // bar 3

    int sc = 0;                                           // (2ps)%6
    for (int ps = 0; ps < 8; ps++) {
      v4f acc3[2];                                // [rr]
      #pragma unroll
      for (int rr = 0; rr < 2; rr++)
        acc3[rr] = (v4f){bv3, bv3, bv3, bv3};

      __builtin_amdgcn_s_setprio(1);
      #pragma unroll
      for (int t = 0; t < 4; t++) {
        const char* srow = a2r + m6(sc + t) * A2ROWB;
        #pragma unroll
        for (int dx = 0; dx < 3; dx++) {
          #pragma unroll
          for (int kb = 0; kb < 2; kb++) {
            int P = Mh * 16 + l15 + dx;             // 0..33
            v8bf af = *(const v8bf*)(srow + (size_t)swz(P * 8 + kb * 4 + q) * 16);
            if (t <= 2)
              acc3[0] = __builtin_amdgcn_mfma_f32_16x16x32_bf16(
                  af, breg3[t * 3 + dx][kb], acc3[0], 0, 0, 0);
            if (t >= 1)
              acc3[1] = __builtin_amdgcn_mfma_f32_16x16x32_bf16(
                  af, breg3[(t - 1) * 3 + dx][kb], acc3[1], 0, 0, 0);
          }
        }
      }
      __builtin_amdgcn_s_setprio(0);

      #pragma unroll
      for (int rr = 0; rr < 2; rr++) {
        size_t rb = ((size_t)b * PADPLANE
                     + (size_t)(y0 + 2 * ps + rr + 1) * PADW + x0 + 1) * 32;
        #pragma unroll
        for (int r = 0; r < 4; r++) {
          int px = Mh * 16 + q * 4 + r;             // 0..31
          act3[rb + (size_t)px * 32 + ntw * 16 + l15] =
              (__bf16)fmaxf(acc3[rr][r], 0.f);
        }
      }
      __builtin_amdgcn_s_barrier();                       // bar 4+ps
      __builtin_amdgcn_sched_barrier(0);
      sc = m6(sc + 2);
    }
  }
}

// ---------------------------------------------------------------------------
// conv4 (32->1): LDS-staged act3 reads (unchanged).
// ---------------------------------------------------------------------------
#define C4ROWB 16512   // 258 px * 32 ch * 2 B = 1032 chunks
__global__ __launch_bounds__(256, 2) void conv4_k(
    const __bf16* __restrict__ act3, const float* __restrict__ w4t,
    const float* __restrict__ b4, const float* __restrict__ sfp,
    float* __restrict__ dout)
{
  const int x = threadIdx.x, lane = threadIdx.x & 63, wave = threadIdx.x >> 6;
  const int y0 = blockIdx.x * 2, b = blockIdx.y;
  const float b4v = b4[0], sf = sfp[0];
  const __bf16* plane = act3 + (size_t)b * PADPLANE * 32;
  __shared__ __align__(16) char smem[4 * C4ROWB];

  #pragma unroll
  for (int r = 0; r < 4; r++) {
    const char* g = (const char*)(plane + (size_t)(y0 + r) * PADW * 32);
    char* lrow = smem + r * C4ROWB;
    #pragma unroll
    for (int k = 0; k < 4; k++) {
      int c = k * 256 + wave * 64 + lane;
      gl_lds(g + (size_t)swz(c) * 16, lrow + (k * 256 + wave * 64) * 16);
    }
    if (wave == 0 && lane < 8) {
      int c = 1024 + lane;
      gl_lds(g + (size_t)swz(c) * 16, lrow + 1024 * 16);
    }
  }
  asm volatile("s_waitcnt vmcnt(0)" ::: "memory");
  __builtin_amdgcn_s_barrier();

  float acc0 = b4v, acc1 = b4v;
  #pragma unroll
  for (int t = 0; t < 4; t++) {
    const char* srow = smem + t * C4ROWB;
    uint4 L[12];
    #pragma unroll
    for (int j = 0; j < 12; j++) {
      int chunk = (x + (j >> 2)) * 4 + (j & 3);
      L[j] = *(const uint4*)(srow + (size_t)swz(chunk) * 16);
    }
    #pragma unroll
    for (int j = 0; j < 12; j++) {
      const int dx = j >> 2, c0 = (j & 3) * 8;
      unsigned int uu[4] = {L[j].x, L[j].y, L[j].z, L[j].w};
      float f[8];
      #pragma unroll
      for (int k = 0; k < 4; k++) {
        f[2*k]   = __builtin_bit_cast(float, uu[k] << 16);
        f[2*k+1] = __builtin_bit_cast(float, uu[k] & 0xFFFF0000u);
      }
      if (t <= 2) {
        const float* wp = w4t + (t * 3 + dx) * 32 + c0;          // uniform
        #pragma unroll
        for (int k = 0; k < 8; k++) acc0 = fmaf(wp[k], f[k], acc0);
      }
      if (t >= 1) {
        const float* wp = w4t + ((t - 1) * 3 + dx) * 32 + c0;    // uniform
        #pragma unroll
        for (int k = 0; k < 8; k++) acc1 = fmaf(wp[k], f[k], acc1);
      }
    }
  }
  size_t p0 = ((size_t)b << 16) + (size_t)y0 * WIDTH + x;
  float vh0 = acc0 * sf, vh1 = acc1 * sf;
  dout[p0]                   = dout[524288 + p0] + vh0;          // outputs
  dout[2621440 + p0]         = vh0;                              // V_hat
  dout[p0 + WIDTH]           = dout[524288 + p0 + WIDTH] + vh1;
  dout[2621440 + p0 + WIDTH] = vh1;
}

// ---------------------------------------------------------------------------
extern "C" void kernel_launch(void* const* d_in, const int* in_sizes, int n_in,
                              void* d_out, int out_size, void* d_ws, size_t ws_size,
                              hipStream_t stream) {
  const float* inputs = (const float*)d_in[0];
  const float* H0     = (const float*)d_in[1];
  const float* C0     = (const float*)d_in[2];
  const float* c2     = (const float*)d_in[3];
  const float* sf     = (const float*)d_in[4];
  const float* w1     = (const float*)d_in[5];
  const float* b1     = (const float*)d_in[6];
  const float* w2     = (const float*)d_in[7];
  const float* b2     = (const float*)d_in[8];
  const float* w3     = (const float*)d_in[9];
  const float* b3     = (const float*)d_in[10];
  const float* w4     = (const float*)d_in[11];
  const float* b4     = (const float*)d_in[12];
  float* out = (float*)d_out;
  float* ws  = (float*)d_ws;

  float*  w1t  = ws;                               // 288 fp32
  float*  w4t  = ws + 288;                         // 288 fp32
  __bf16* B2t  = (__bf16*)(ws + 576);              // 18432 bf16
  __bf16* B3t  = (__bf16*)(ws + 9792);             // 18432 bf16
  __bf16* act1 = (__bf16*)(ws + 19008);            // 8*66564*32 bf16
  __bf16* act3 = act1 + (size_t)8 * PADPLANE * 32; // 8*66564*32 bf16

  wz_k<<<1175, 256, 0, stream>>>(w1, w2, w3, w4, w1t, B2t, B3t, w4t,
                                 act1, act3);
  prepconv1_k<<<dim3(256, 8), 256, 0, stream>>>(inputs, H0, C0, c2, sf,
                                                w1t, b1, out, act1);
  conv23_k<<<dim3(16, 8, 8), 512, 0, stream>>>(act1, B2t, b2, B3t, b3, act3);
  conv4_k<<<dim3(128, 8), 256, 0, stream>>>(act3, w4t, b4, sf, out);
}

// Round 9
// 171.658 us; speedup vs baseline: 2.1638x; 2.1638x over previous
//
#include <hip/hip_runtime.h>

#define PLANE 65536
#define WIDTH 256
#define PADW 258
#define PADPLANE 66564   // 258*258

typedef __bf16 v8bf __attribute__((ext_vector_type(8)));
typedef float  v4f  __attribute__((ext_vector_type(4)));

typedef const __attribute__((address_space(1))) unsigned int* gas_ptr;
typedef __attribute__((address_space(3))) unsigned int* las_ptr;

// async global->LDS, 16 B per lane; LDS dest = wave-uniform base + lane*16
__device__ __forceinline__ void gl_lds(const void* g, void* l) {
  __builtin_amdgcn_global_load_lds((gas_ptr)g, (las_ptr)l, 16, 0, 0);
}

// self-inverse 16B-chunk swizzle within 8-chunk groups
__device__ __forceinline__ int swz(int c) {
  return (c & ~7) | ((c & 7) ^ ((c >> 3) & 7));
}

__device__ __forceinline__ int m6(int x) { return x >= 6 ? x - 6 : x; }

__device__ __forceinline__ unsigned int pack2(float a, float b) {
  __bf16 ba = (__bf16)a, bb = (__bf16)b;
  unsigned short sa = __builtin_bit_cast(unsigned short, ba);
  unsigned short sb = __builtin_bit_cast(unsigned short, bb);
  return (unsigned int)sa | ((unsigned int)sb << 16);
}

// ---------------------------------------------------------------------------
// wz_k: fused weight-prep + padding-ring zeroing (act1 + act3 only).
// ---------------------------------------------------------------------------
#define WT_N 37440                       // 288+18432+18432+288
#define ZR_N (8 * 1028 * 32)             // 16+16 uints per ring px
__global__ __launch_bounds__(256) void wz_k(
    const float* __restrict__ w1, const float* __restrict__ w2,
    const float* __restrict__ w3, const float* __restrict__ w4,
    float* __restrict__ w1t, __bf16* __restrict__ B2t,
    __bf16* __restrict__ B3t, float* __restrict__ w4t,
    __bf16* __restrict__ a1, __bf16* __restrict__ a3)
{
  int t = blockIdx.x * 256 + threadIdx.x;
  if (t < WT_N) {
    if (t < 288) {                       // w1: [32][1][9] -> [tap][32]
      int tap = t >> 5, cout = t & 31;
      w1t[t] = w1[cout * 9 + tap];
    }
    int t2 = t - 288;
    if (t2 >= 0 && t2 < 18432) {         // 64 x 288
      int cout = t2 / 288, k = t2 % 288;
      int tap = k / 32, cin = k % 32;
      B2t[t2] = (__bf16)w2[cout * 288 + cin * 9 + tap];
    }
    int t3 = t - (288 + 18432);
    if (t3 >= 0 && t3 < 18432) {         // 32 x 576
      int cout = t3 / 576, k = t3 % 576;
      int tap = k / 64, cin = k % 64;
      B3t[t3] = (__bf16)w3[cout * 576 + cin * 9 + tap];
    }
    int t4 = t - (288 + 18432 + 18432);
    if (t4 >= 0 && t4 < 288) {           // w4: [1][32][9] -> [tap][32]
      int tap = t4 >> 5, cin = t4 & 31;
      w4t[t4] = w4[cin * 9 + tap];
    }
    return;
  }
  int idx = t - WT_N;
  if (idx >= ZR_N) return;
  unsigned int* p;
  const int R1 = 8 * 1028 * 16;
  if (idx < R1) p = (unsigned int*)a1;
  else         { p = (unsigned int*)a3; idx -= R1; }
  int ch = idx & 15;
  int pr = idx >> 4;                 // 0 .. 8*1028-1
  int b = pr / 1028, r = pr % 1028;
  int y, x;
  if      (r < 258) { y = 0;           x = r; }
  else if (r < 516) { y = 257;         x = r - 258; }
  else if (r < 772) { y = r - 516 + 1; x = 0; }
  else              { y = r - 772 + 1; x = 257; }
  p[((size_t)b * PADPLANE + y * PADW + x) * 16 + ch] = 0;
}

// ---------------------------------------------------------------------------
// prepconv1_k: fused prep + conv1 (unchanged).
// ---------------------------------------------------------------------------
__global__ __launch_bounds__(256) void prepconv1_k(
    const float* __restrict__ inputs, const float* __restrict__ H0,
    const float* __restrict__ C0, const float* __restrict__ c2p,
    const float* __restrict__ sfp, const float* __restrict__ w1t,
    const float* __restrict__ b1, float* __restrict__ dout,
    __bf16* __restrict__ act1)
{
  const int x = threadIdx.x, y = blockIdx.x, b = blockIdx.y;
  const int p = b * PLANE + y * WIDTH + x;
  const float c2 = c2p[0], sf = sfp[0], rsf = 1.0f / sf;

  float iv[3][3], hv[3][3];
  #pragma unroll
  for (int dy = 0; dy < 3; dy++) {
    int yy = y + dy - 1;
    #pragma unroll
    for (int dx = 0; dx < 3; dx++) {
      int xx = x + dx - 1;
      bool ok = (yy >= 0 && yy < 256 && xx >= 0 && xx < 256);
      int pn = p + (dy - 1) * WIDTH + (dx - 1);
      iv[dy][dx] = ok ? inputs[pn] : 0.f;
      hv[dy][dx] = ok ? H0[pn]     : 0.f;
    }
  }
  const float in = iv[1][1], h0 = hv[1][1];
  const float c0a = C0[b * 131072 + y * WIDTH + x];
  float lap = iv[0][1] + iv[2][1] + iv[1][0] + iv[1][2] - 4.f * in;
  float Hv = 2.f * in - c0a + c2 * lap;
  float V  = in - h0;
  dout[524288 + p]  = Hv;                               // H
  dout[2097152 + p] = V;                                // V
  dout[1048576 + b * 131072 + y * WIDTH + x]         = in;   // C_new[:,0]
  dout[1048576 + b * 131072 + 65536 + y * WIDTH + x] = c0a;  // C_new[:,1]

  float acc[32];
  #pragma unroll
  for (int i = 0; i < 32; i++) acc[i] = b1[i];
  #pragma unroll
  for (int tap = 0; tap < 9; tap++) {
    float v = (iv[tap / 3][tap % 3] - hv[tap / 3][tap % 3]) * rsf;
    const float* wp = w1t + tap * 32;                   // uniform
    #pragma unroll
    for (int i = 0; i < 32; i++) acc[i] = fmaf(wp[i], v, acc[i]);
  }
  unsigned int u[16];
  #pragma unroll
  for (int j = 0; j < 16; j++)
    u[j] = pack2(fmaxf(acc[2*j], 0.f), fmaxf(acc[2*j+1], 0.f));
  size_t pa = ((size_t)b * PADPLANE + (y+1) * PADW + (x+1)) * 32;
  uint4* op = reinterpret_cast<uint4*>(act1 + pa);
  #pragma unroll
  for (int j = 0; j < 4; j++)
    op[j] = make_uint4(u[4*j], u[4*j+1], u[4*j+2], u[4*j+3]);
}

// ---------------------------------------------------------------------------
// conv23_k: FUSED conv2+conv3, producer/consumer wave specialization.
//
// ROUND-9: r8's x32 tile achieved 4 blocks/CU (Occupancy 87%) but
// __launch_bounds__(512,8) clamped the allocator to 32 VGPR -> ~740 MB of
// scratch spill traffic (FETCH 574 MB), 260 us. Fix: bounds back to (512,4)
// — the allocator targets <=128, lands ~64 like r7, and 64 VGPR already
// permits 8 waves/SIMD (m69: waves halve at 64/128/256). Occupancy stays
// LDS-limited at 4 blocks/CU. NO other change vs r8.
// ---------------------------------------------------------------------------
#define A1ROWB 2304   // 36 px * 32 ch * 2 B = 144 chunks
#define A2ROWB 4352   // 34 px * 64 ch * 2 B = 272 chunks
__global__ __launch_bounds__(512, 4) void conv23_k(
    const __bf16* __restrict__ act1, const __bf16* __restrict__ B2t,
    const float* __restrict__ b2, const __bf16* __restrict__ B3t,
    const float* __restrict__ b3, __bf16* __restrict__ act3)
{
  const int lane = threadIdx.x & 63, wave = threadIdx.x >> 6;
  const int l15 = lane & 15, q = lane >> 4;
  const int y0 = blockIdx.x * 16, xt = blockIdx.y, b = blockIdx.z;
  const int x0 = xt * 32;
  __shared__ __align__(16) char smem[6 * A2ROWB + 6 * A1ROWB + 1024];
  char* a2r = smem;                       // act2 ring (6 slots)
  char* a1r = smem + 6 * A2ROWB;          // act1 ring (6 slots; +1KB pad for
                                          //  ragged m-tile over-reads)
  const __bf16* plane = act1 + (size_t)b * PADPLANE * 32;

  if (wave < 4) {
    // ------------------------- PRODUCER (conv2) -------------------------
    auto stageA1 = [&](int k, int slot) {  // a1 rel row k = padded y0-1+k
      int a = y0 - 1 + k;
      a = a < 0 ? 0 : (a > 257 ? 257 : a);
      // 144 chunks/row, 36 per wave (exec-masked gl_lds)
      const char* g = (const char*)(plane + ((size_t)a * PADW + x0 - 1) * 32);
      char* lrow = a1r + slot * A1ROWB;
      const int base = wave * 36;
      if (lane < 36)
        gl_lds(g + (size_t)swz(base + lane) * 16, lrow + base * 16);
    };

    v8bf breg2[9];                         // this wave's 16 couts
    #pragma unroll
    for (int tap = 0; tap < 9; tap++)
      breg2[tap] = *(const v8bf*)(B2t + (size_t)(wave * 16 + l15) * 288
                                      + tap * 32 + q * 8);
    const v4f bv2 = *(const v4f*)(b2 + wave * 16 + q * 4);

    auto zrow = [&](int sl) {              // zero a2 ring slot (272 chunks)
      char* drow = a2r + sl * A2ROWB;
      int c = threadIdx.x;                 // P-group: 0..255
      *(uint4*)(drow + (size_t)c * 16) = make_uint4(0,0,0,0);
      if (c < 16)
        *(uint4*)(drow + (size_t)(c + 256) * 16) = make_uint4(0,0,0,0);
    };

    // produce a2 rel rows t and t+1 (slots s, s+1); each a1 row read ONCE
    auto producePair = [&](int t, int s) {
      const int s1 = m6(s + 1);
      const bool z0 = (y0 + t == 0) || (y0 + t == 257);
      const bool z1 = (y0 + t + 1 == 0) || (y0 + t + 1 == 257);
      if (z0) zrow(s);
      if (z1) zrow(s1);
      if (z0 && z1) return;
      v4f acc0[3], acc1v[3];
      #pragma unroll
      for (int m = 0; m < 3; m++) { acc0[m] = bv2; acc1v[m] = bv2; }
      #pragma unroll
      for (int r = 0; r < 4; r++) {        // a1 rel row t+r (dy=r for row t)
        if (z0 && r == 0) continue;        // r0 feeds only row t
        if (z1 && r == 3) continue;        // r3 feeds only row t+1
        const char* srow = a1r + m6(s + r) * A1ROWB;
        #pragma unroll
        for (int dx = 0; dx < 3; dx++) {
          #pragma unroll
          for (int m = 0; m < 3; m++) {
            int j = m * 16 + l15 + dx;     // >35 over-reads: garbage, unused
            v8bf af = *(const v8bf*)(srow + (size_t)swz(j * 4 + q) * 16);
            if (!z0 && r <= 2)             // row t, tap (dy=r, dx)
              acc0[m] = __builtin_amdgcn_mfma_f32_16x16x32_bf16(
                  breg2[r * 3 + dx], af, acc0[m], 0, 0, 0);
            if (!z1 && r >= 1)             // row t+1, tap (dy=r-1, dx)
              acc1v[m] = __builtin_amdgcn_mfma_f32_16x16x32_bf16(
                  breg2[(r - 1) * 3 + dx], af, acc1v[m], 0, 0, 0);
          }
        }
      }
      const int c = wave * 2 + (q >> 1), boff = (q & 1) * 8;
      #pragma unroll
      for (int rr = 0; rr < 2; rr++) {
        if (rr == 0 && z0) continue;
        if (rr == 1 && z1) continue;
        char* drow = a2r + (rr ? s1 : s) * A2ROWB;
        v4f* A = rr ? acc1v : acc0;
        #pragma unroll
        for (int m = 0; m < 3; m++) {
          int px = m * 16 + l15;
          bool w = (m < 2) || (l15 < 2);               // px <= 33
          if (x0 == 0   && px == 0)  w = false;        // x-halo -> zeroed
          if (x0 == 224 && px == 33) w = false;
          if (w) {
            unsigned int lo = pack2(fmaxf(A[m][0], 0.f), fmaxf(A[m][1], 0.f));
            unsigned int hi = pack2(fmaxf(A[m][2], 0.f), fmaxf(A[m][3], 0.f));
            *(uint2*)(drow + (size_t)swz(px * 8 + c) * 16 + boff)
                = make_uint2(lo, hi);
          }
        }
        if (x0 == 0 && threadIdx.x < 8)            // zero px slot 0 (halo)
          *(uint4*)(drow + (size_t)swz(threadIdx.x) * 16) = make_uint4(0,0,0,0);
        if (x0 == 224 && threadIdx.x < 8)          // zero px slot 33 (halo)
          *(uint4*)(drow + (size_t)swz(264 + threadIdx.x) * 16) = make_uint4(0,0,0,0);
      }
    };

    // prologue: a1 rows 0..5; produce a2 rows 0..3; a1 rows 6,7
    #pragma unroll
    for (int k = 0; k < 6; k++) stageA1(k, k);
    asm volatile("s_waitcnt vmcnt(0)" ::: "memory");
    __builtin_amdgcn_s_barrier();                         // bar 1
    __builtin_amdgcn_sched_barrier(0);
    producePair(0, 0); producePair(2, 2);
    asm volatile("s_waitcnt lgkmcnt(0)" ::: "memory");
    __builtin_amdgcn_s_barrier();                         // bar 2
    __builtin_amdgcn_sched_barrier(0);
    stageA1(6, 0); stageA1(7, 1);
    asm volatile("s_waitcnt vmcnt(0)" ::: "memory");
    __builtin_amdgcn_s_barrier();                         // bar 3
    __builtin_amdgcn_sched_barrier(0);

    int sb = 2;                                           // (2ps+2)%6
    for (int ps = 0; ps < 8; ps++) {
      // stage a1 rows 2ps+8,9 (clamped; land in just-freed slots)
      int r0 = 2 * ps + 8, r1 = 2 * ps + 9;
      stageA1(r0 > 19 ? 19 : r0, sb);
      stageA1(r1 > 19 ? 19 : r1, m6(sb + 1));
      // produce a2 rows 2ps+4,5 (a1 rows 2ps+4..2ps+7 staged+drained)
      if (2 * ps + 4 <= 17) producePair(2 * ps + 4, m6(sb + 2));
      // own-wave drains BEFORE the shared barrier (cross-wave visibility)
      asm volatile("s_waitcnt vmcnt(0) lgkmcnt(0)" ::: "memory");
      __builtin_amdgcn_s_barrier();                       // bar 4+ps
      __builtin_amdgcn_sched_barrier(0);
      sb = m6(sb + 2);
    }
  } else {
    // ------------------------- CONSUMER (conv3) -------------------------
    const int cw = wave - 4;
    const int Mh = cw >> 1, ntw = cw & 1;  // px 16-tile, cout half
    v8bf breg3[9][2];                          // tap, kb
    #pragma unroll
    for (int tap = 0; tap < 9; tap++)
      #pragma unroll
      for (int kb = 0; kb < 2; kb++)
        breg3[tap][kb] = *(const v8bf*)(B3t + (size_t)(ntw * 16 + l15) * 576
                                            + tap * 64 + kb * 32 + q * 8);
    const float bv3 = b3[ntw * 16 + l15];

    __builtin_amdgcn_s_barrier();                         // bar 1
    __builtin_amdgcn_s_barrier();                         // bar 2
    __builtin_amdgcn_s_barrier();                         // bar 3

    int sc = 0;                                           // (2ps)%6
    for (int ps = 0; ps < 8; ps++) {
      v4f acc3[2];                                // [rr]
      #pragma unroll
      for (int rr = 0; rr < 2; rr++)
        acc3[rr] = (v4f){bv3, bv3, bv3, bv3};

      __builtin_amdgcn_s_setprio(1);
      #pragma unroll
      for (int t = 0; t < 4; t++) {
        const char* srow = a2r + m6(sc + t) * A2ROWB;
        #pragma unroll
        for (int dx = 0; dx < 3; dx++) {
          #pragma unroll
          for (int kb = 0; kb < 2; kb++) {
            int P = Mh * 16 + l15 + dx;             // 0..33
            v8bf af = *(const v8bf*)(srow + (size_t)swz(P * 8 + kb * 4 + q) * 16);
            if (t <= 2)
              acc3[0] = __builtin_amdgcn_mfma_f32_16x16x32_bf16(
                  af, breg3[t * 3 + dx][kb], acc3[0], 0, 0, 0);
            if (t >= 1)
              acc3[1] = __builtin_amdgcn_mfma_f32_16x16x32_bf16(
                  af, breg3[(t - 1) * 3 + dx][kb], acc3[1], 0, 0, 0);
          }
        }
      }
      __builtin_amdgcn_s_setprio(0);

      #pragma unroll
      for (int rr = 0; rr < 2; rr++) {
        size_t rb = ((size_t)b * PADPLANE
                     + (size_t)(y0 + 2 * ps + rr + 1) * PADW + x0 + 1) * 32;
        #pragma unroll
        for (int r = 0; r < 4; r++) {
          int px = Mh * 16 + q * 4 + r;             // 0..31
          act3[rb + (size_t)px * 32 + ntw * 16 + l15] =
              (__bf16)fmaxf(acc3[rr][r], 0.f);
        }
      }
      __builtin_amdgcn_s_barrier();                       // bar 4+ps
      __builtin_amdgcn_sched_barrier(0);
      sc = m6(sc + 2);
    }
  }
}

// ---------------------------------------------------------------------------
// conv4 (32->1): LDS-staged act3 reads (unchanged).
// ---------------------------------------------------------------------------
#define C4ROWB 16512   // 258 px * 32 ch * 2 B = 1032 chunks
__global__ __launch_bounds__(256, 2) void conv4_k(
    const __bf16* __restrict__ act3, const float* __restrict__ w4t,
    const float* __restrict__ b4, const float* __restrict__ sfp,
    float* __restrict__ dout)
{
  const int x = threadIdx.x, lane = threadIdx.x & 63, wave = threadIdx.x >> 6;
  const int y0 = blockIdx.x * 2, b = blockIdx.y;
  const float b4v = b4[0], sf = sfp[0];
  const __bf16* plane = act3 + (size_t)b * PADPLANE * 32;
  __shared__ __align__(16) char smem[4 * C4ROWB];

  #pragma unroll
  for (int r = 0; r < 4; r++) {
    const char* g = (const char*)(plane + (size_t)(y0 + r) * PADW * 32);
    char* lrow = smem + r * C4ROWB;
    #pragma unroll
    for (int k = 0; k < 4; k++) {
      int c = k * 256 + wave * 64 + lane;
      gl_lds(g + (size_t)swz(c) * 16, lrow + (k * 256 + wave * 64) * 16);
    }
    if (wave == 0 && lane < 8) {
      int c = 1024 + lane;
      gl_lds(g + (size_t)swz(c) * 16, lrow + 1024 * 16);
    }
  }
  asm volatile("s_waitcnt vmcnt(0)" ::: "memory");
  __builtin_amdgcn_s_barrier();

  float acc0 = b4v, acc1 = b4v;
  #pragma unroll
  for (int t = 0; t < 4; t++) {
    const char* srow = smem + t * C4ROWB;
    uint4 L[12];
    #pragma unroll
    for (int j = 0; j < 12; j++) {
      int chunk = (x + (j >> 2)) * 4 + (j & 3);
      L[j] = *(const uint4*)(srow + (size_t)swz(chunk) * 16);
    }
    #pragma unroll
    for (int j = 0; j < 12; j++) {
      const int dx = j >> 2, c0 = (j & 3) * 8;
      unsigned int uu[4] = {L[j].x, L[j].y, L[j].z, L[j].w};
      float f[8];
      #pragma unroll
      for (int k = 0; k < 4; k++) {
        f[2*k]   = __builtin_bit_cast(float, uu[k] << 16);
        f[2*k+1] = __builtin_bit_cast(float, uu[k] & 0xFFFF0000u);
      }
      if (t <= 2) {
        const float* wp = w4t + (t * 3 + dx) * 32 + c0;          // uniform
        #pragma unroll
        for (int k = 0; k < 8; k++) acc0 = fmaf(wp[k], f[k], acc0);
      }
      if (t >= 1) {
        const float* wp = w4t + ((t - 1) * 3 + dx) * 32 + c0;    // uniform
        #pragma unroll
        for (int k = 0; k < 8; k++) acc1 = fmaf(wp[k], f[k], acc1);
      }
    }
  }
  size_t p0 = ((size_t)b << 16) + (size_t)y0 * WIDTH + x;
  float vh0 = acc0 * sf, vh1 = acc1 * sf;
  dout[p0]                   = dout[524288 + p0] + vh0;          // outputs
  dout[2621440 + p0]         = vh0;                              // V_hat
  dout[p0 + WIDTH]           = dout[524288 + p0 + WIDTH] + vh1;
  dout[2621440 + p0 + WIDTH] = vh1;
}

// ---------------------------------------------------------------------------
extern "C" void kernel_launch(void* const* d_in, const int* in_sizes, int n_in,
                              void* d_out, int out_size, void* d_ws, size_t ws_size,
                              hipStream_t stream) {
  const float* inputs = (const float*)d_in[0];
  const float* H0     = (const float*)d_in[1];
  const float* C0     = (const float*)d_in[2];
  const float* c2     = (const float*)d_in[3];
  const float* sf     = (const float*)d_in[4];
  const float* w1     = (const float*)d_in[5];
  const float* b1     = (const float*)d_in[6];
  const float* w2     = (const float*)d_in[7];
  const float* b2     = (const float*)d_in[8];
  const float* w3     = (const float*)d_in[9];
  const float* b3     = (const float*)d_in[10];
  const float* w4     = (const float*)d_in[11];
  const float* b4     = (const float*)d_in[12];
  float* out = (float*)d_out;
  float* ws  = (float*)d_ws;

  float*  w1t  = ws;                               // 288 fp32
  float*  w4t  = ws + 288;                         // 288 fp32
  __bf16* B2t  = (__bf16*)(ws + 576);              // 18432 bf16
  __bf16* B3t  = (__bf16*)(ws + 9792);             // 18432 bf16
  __bf16* act1 = (__bf16*)(ws + 19008);            // 8*66564*32 bf16
  __bf16* act3 = act1 + (size_t)8 * PADPLANE * 32; // 8*66564*32 bf16

  wz_k<<<1175, 256, 0, stream>>>(w1, w2, w3, w4, w1t, B2t, B3t, w4t,
                                 act1, act3);
  prepconv1_k<<<dim3(256, 8), 256, 0, stream>>>(inputs, H0, C0, c2, sf,
                                                w1t, b1, out, act1);
  conv23_k<<<dim3(16, 8, 8), 512, 0, stream>>>(act1, B2t, b2, B3t, b3, act3);
  conv4_k<<<dim3(128, 8), 256, 0, stream>>>(act3, w4t, b4, sf, out);
}

// Round 10
// 162.652 us; speedup vs baseline: 2.2836x; 1.0554x over previous
//
#include <hip/hip_runtime.h>

#define PLANE 65536
#define WIDTH 256
#define PADW 258
#define PADPLANE 66564   // 258*258

typedef __bf16 v8bf __attribute__((ext_vector_type(8)));
typedef float  v4f  __attribute__((ext_vector_type(4)));

typedef const __attribute__((address_space(1))) unsigned int* gas_ptr;
typedef __attribute__((address_space(3))) unsigned int* las_ptr;

// async global->LDS, 16 B per lane; LDS dest = wave-uniform base + lane*16
__device__ __forceinline__ void gl_lds(const void* g, void* l) {
  __builtin_amdgcn_global_load_lds((gas_ptr)g, (las_ptr)l, 16, 0, 0);
}

// self-inverse 16B-chunk swizzle within 8-chunk groups
__device__ __forceinline__ int swz(int c) {
  return (c & ~7) | ((c & 7) ^ ((c >> 3) & 7));
}

__device__ __forceinline__ int m6(int x) { return x >= 6 ? x - 6 : x; }

__device__ __forceinline__ unsigned int pack2(float a, float b) {
  __bf16 ba = (__bf16)a, bb = (__bf16)b;
  unsigned short sa = __builtin_bit_cast(unsigned short, ba);
  unsigned short sb = __builtin_bit_cast(unsigned short, bb);
  return (unsigned int)sa | ((unsigned int)sb << 16);
}

// ---------------------------------------------------------------------------
// wz_k: fused weight-prep + padding-ring zeroing (act1 + act3 only).
// ---------------------------------------------------------------------------
#define WT_N 37440                       // 288+18432+18432+288
#define ZR_N (8 * 1028 * 32)             // 16+16 uints per ring px
__global__ __launch_bounds__(256) void wz_k(
    const float* __restrict__ w1, const float* __restrict__ w2,
    const float* __restrict__ w3, const float* __restrict__ w4,
    float* __restrict__ w1t, __bf16* __restrict__ B2t,
    __bf16* __restrict__ B3t, float* __restrict__ w4t,
    __bf16* __restrict__ a1, __bf16* __restrict__ a3)
{
  int t = blockIdx.x * 256 + threadIdx.x;
  if (t < WT_N) {
    if (t < 288) {                       // w1: [32][1][9] -> [tap][32]
      int tap = t >> 5, cout = t & 31;
      w1t[t] = w1[cout * 9 + tap];
    }
    int t2 = t - 288;
    if (t2 >= 0 && t2 < 18432) {         // 64 x 288
      int cout = t2 / 288, k = t2 % 288;
      int tap = k / 32, cin = k % 32;
      B2t[t2] = (__bf16)w2[cout * 288 + cin * 9 + tap];
    }
    int t3 = t - (288 + 18432);
    if (t3 >= 0 && t3 < 18432) {         // 32 x 576
      int cout = t3 / 576, k = t3 % 576;
      int tap = k / 64, cin = k % 64;
      B3t[t3] = (__bf16)w3[cout * 576 + cin * 9 + tap];
    }
    int t4 = t - (288 + 18432 + 18432);
    if (t4 >= 0 && t4 < 288) {           // w4: [1][32][9] -> [tap][32]
      int tap = t4 >> 5, cin = t4 & 31;
      w4t[t4] = w4[cin * 9 + tap];
    }
    return;
  }
  int idx = t - WT_N;
  if (idx >= ZR_N) return;
  unsigned int* p;
  const int R1 = 8 * 1028 * 16;
  if (idx < R1) p = (unsigned int*)a1;
  else         { p = (unsigned int*)a3; idx -= R1; }
  int ch = idx & 15;
  int pr = idx >> 4;                 // 0 .. 8*1028-1
  int b = pr / 1028, r = pr % 1028;
  int y, x;
  if      (r < 258) { y = 0;           x = r; }
  else if (r < 516) { y = 257;         x = r - 258; }
  else if (r < 772) { y = r - 516 + 1; x = 0; }
  else              { y = r - 772 + 1; x = 257; }
  p[((size_t)b * PADPLANE + y * PADW + x) * 16 + ch] = 0;
}

// ---------------------------------------------------------------------------
// prepconv1_k: fused prep + conv1 (unchanged).
// ---------------------------------------------------------------------------
__global__ __launch_bounds__(256) void prepconv1_k(
    const float* __restrict__ inputs, const float* __restrict__ H0,
    const float* __restrict__ C0, const float* __restrict__ c2p,
    const float* __restrict__ sfp, const float* __restrict__ w1t,
    const float* __restrict__ b1, float* __restrict__ dout,
    __bf16* __restrict__ act1)
{
  const int x = threadIdx.x, y = blockIdx.x, b = blockIdx.y;
  const int p = b * PLANE + y * WIDTH + x;
  const float c2 = c2p[0], sf = sfp[0], rsf = 1.0f / sf;

  float iv[3][3], hv[3][3];
  #pragma unroll
  for (int dy = 0; dy < 3; dy++) {
    int yy = y + dy - 1;
    #pragma unroll
    for (int dx = 0; dx < 3; dx++) {
      int xx = x + dx - 1;
      bool ok = (yy >= 0 && yy < 256 && xx >= 0 && xx < 256);
      int pn = p + (dy - 1) * WIDTH + (dx - 1);
      iv[dy][dx] = ok ? inputs[pn] : 0.f;
      hv[dy][dx] = ok ? H0[pn]     : 0.f;
    }
  }
  const float in = iv[1][1], h0 = hv[1][1];
  const float c0a = C0[b * 131072 + y * WIDTH + x];
  float lap = iv[0][1] + iv[2][1] + iv[1][0] + iv[1][2] - 4.f * in;
  float Hv = 2.f * in - c0a + c2 * lap;
  float V  = in - h0;
  dout[524288 + p]  = Hv;                               // H
  dout[2097152 + p] = V;                                // V
  dout[1048576 + b * 131072 + y * WIDTH + x]         = in;   // C_new[:,0]
  dout[1048576 + b * 131072 + 65536 + y * WIDTH + x] = c0a;  // C_new[:,1]

  float acc[32];
  #pragma unroll
  for (int i = 0; i < 32; i++) acc[i] = b1[i];
  #pragma unroll
  for (int tap = 0; tap < 9; tap++) {
    float v = (iv[tap / 3][tap % 3] - hv[tap / 3][tap % 3]) * rsf;
    const float* wp = w1t + tap * 32;                   // uniform
    #pragma unroll
    for (int i = 0; i < 32; i++) acc[i] = fmaf(wp[i], v, acc[i]);
  }
  unsigned int u[16];
  #pragma unroll
  for (int j = 0; j < 16; j++)
    u[j] = pack2(fmaxf(acc[2*j], 0.f), fmaxf(acc[2*j+1], 0.f));
  size_t pa = ((size_t)b * PADPLANE + (y+1) * PADW + (x+1)) * 32;
  uint4* op = reinterpret_cast<uint4*>(act1 + pa);
  #pragma unroll
  for (int j = 0; j < 4; j++)
    op[j] = make_uint4(u[4*j], u[4*j+1], u[4*j+2], u[4*j+3]);
}

// ---------------------------------------------------------------------------
// conv23_k: FUSED conv2+conv3, producer/consumer wave specialization.
// ROUND-10: REVERT to the measured-best r7 geometry (x64 tile, ROWS=16,
// bounds(512,4) — 52.6 us; the r9 x32 tile cost +15% instructions and the
// hoped-for occupancy never materialized). One new edit on top:
// conv3 operand SWAP (mfma(breg3, af) -> D[cout][px], r5-verified pattern):
// lane holds 4 consecutive couts for one px -> act3 epilogue = 4x
// global_store_dwordx2 per wave-step instead of 16x scalar 2-B stores.
// Same per-output K-dot order -> bit-identical.
// ---------------------------------------------------------------------------
#define A1ROWB 4352   // 68 px * 32 ch * 2 B = 272 chunks
#define A2ROWB 8448   // 66 px * 64 ch * 2 B = 528 chunks
__global__ __launch_bounds__(512, 4) void conv23_k(
    const __bf16* __restrict__ act1, const __bf16* __restrict__ B2t,
    const float* __restrict__ b2, const __bf16* __restrict__ B3t,
    const float* __restrict__ b3, __bf16* __restrict__ act3)
{
  const int lane = threadIdx.x & 63, wave = threadIdx.x >> 6;
  const int l15 = lane & 15, q = lane >> 4;
  const int y0 = blockIdx.x * 16, xt = blockIdx.y, b = blockIdx.z;
  const int x0 = xt * 64;
  __shared__ __align__(16) char smem[6 * A2ROWB + 6 * A1ROWB + 1024];
  char* a2r = smem;                       // act2 ring (6 slots)
  char* a1r = smem + 6 * A2ROWB;          // act1 ring (6 slots; +1KB pad for
                                          //  ragged m-tile over-reads)
  const __bf16* plane = act1 + (size_t)b * PADPLANE * 32;

  if (wave < 4) {
    // ------------------------- PRODUCER (conv2) -------------------------
    auto stageA1 = [&](int k, int slot) {  // a1 rel row k = padded y0-1+k
      int a = y0 - 1 + k;
      a = a < 0 ? 0 : (a > 257 ? 257 : a);
      const char* g = (const char*)(plane + ((size_t)a * PADW + x0 - 1) * 32);
      char* lrow = a1r + slot * A1ROWB;
      const int base = wave * 68;
      gl_lds(g + (size_t)swz(base + lane) * 16, lrow + base * 16);
      if (lane < 4)
        gl_lds(g + (size_t)swz(base + 64 + lane) * 16, lrow + (base + 64) * 16);
    };

    v8bf breg2[9];                         // this wave's 16 couts
    #pragma unroll
    for (int tap = 0; tap < 9; tap++)
      breg2[tap] = *(const v8bf*)(B2t + (size_t)(wave * 16 + l15) * 288
                                      + tap * 32 + q * 8);
    const v4f bv2 = *(const v4f*)(b2 + wave * 16 + q * 4);

    auto zrow = [&](int sl) {              // zero a2 ring slot (pad row)
      char* drow = a2r + sl * A2ROWB;
      int c = threadIdx.x;                 // P-group: 0..255
      *(uint4*)(drow + (size_t)c * 16)         = make_uint4(0,0,0,0);
      *(uint4*)(drow + (size_t)(c + 256) * 16) = make_uint4(0,0,0,0);
      if (c < 16)
        *(uint4*)(drow + (size_t)(c + 512) * 16) = make_uint4(0,0,0,0);
    };

    // produce a2 rel rows t and t+1 (slots s, s+1); each a1 row read ONCE
    auto producePair = [&](int t, int s) {
      const int s1 = m6(s + 1);
      const bool z0 = (y0 + t == 0) || (y0 + t == 257);
      const bool z1 = (y0 + t + 1 == 0) || (y0 + t + 1 == 257);
      if (z0) zrow(s);
      if (z1) zrow(s1);
      if (z0 && z1) return;
      v4f acc0[5], acc1v[5];
      #pragma unroll
      for (int m = 0; m < 5; m++) { acc0[m] = bv2; acc1v[m] = bv2; }
      #pragma unroll
      for (int r = 0; r < 4; r++) {        // a1 rel row t+r (dy=r for row t)
        if (z0 && r == 0) continue;        // r0 feeds only row t
        if (z1 && r == 3) continue;        // r3 feeds only row t+1
        const char* srow = a1r + m6(s + r) * A1ROWB;
        #pragma unroll
        for (int dx = 0; dx < 3; dx++) {
          #pragma unroll
          for (int m = 0; m < 5; m++) {
            int j = m * 16 + l15 + dx;     // >67 over-reads: garbage, unused
            v8bf af = *(const v8bf*)(srow + (size_t)swz(j * 4 + q) * 16);
            if (!z0 && r <= 2)             // row t, tap (dy=r, dx)
              acc0[m] = __builtin_amdgcn_mfma_f32_16x16x32_bf16(
                  breg2[r * 3 + dx], af, acc0[m], 0, 0, 0);
            if (!z1 && r >= 1)             // row t+1, tap (dy=r-1, dx)
              acc1v[m] = __builtin_amdgcn_mfma_f32_16x16x32_bf16(
                  breg2[(r - 1) * 3 + dx], af, acc1v[m], 0, 0, 0);
          }
        }
      }
      const int c = wave * 2 + (q >> 1), boff = (q & 1) * 8;
      #pragma unroll
      for (int rr = 0; rr < 2; rr++) {
        if (rr == 0 && z0) continue;
        if (rr == 1 && z1) continue;
        char* drow = a2r + (rr ? s1 : s) * A2ROWB;
        v4f* A = rr ? acc1v : acc0;
        #pragma unroll
        for (int m = 0; m < 5; m++) {
          int px = m * 16 + l15;
          bool w = (m < 4) || (l15 < 2);               // px <= 65
          if (x0 == 0   && px == 0)  w = false;        // x-halo -> zeroed
          if (x0 == 192 && px == 65) w = false;
          if (w) {
            unsigned int lo = pack2(fmaxf(A[m][0], 0.f), fmaxf(A[m][1], 0.f));
            unsigned int hi = pack2(fmaxf(A[m][2], 0.f), fmaxf(A[m][3], 0.f));
            *(uint2*)(drow + (size_t)swz(px * 8 + c) * 16 + boff)
                = make_uint2(lo, hi);
          }
        }
        if (x0 == 0 && threadIdx.x < 8)            // zero px slot 0 (x=-1)
          *(uint4*)(drow + (size_t)swz(threadIdx.x) * 16) = make_uint4(0,0,0,0);
        if (x0 == 192 && threadIdx.x < 8)          // zero px slot 65 (x=256)
          *(uint4*)(drow + (size_t)swz(520 + threadIdx.x) * 16) = make_uint4(0,0,0,0);
      }
    };

    // prologue: a1 rows 0..5; produce a2 rows 0..3; a1 rows 6,7
    #pragma unroll
    for (int k = 0; k < 6; k++) stageA1(k, k);
    asm volatile("s_waitcnt vmcnt(0)" ::: "memory");
    __builtin_amdgcn_s_barrier();                         // bar 1
    __builtin_amdgcn_sched_barrier(0);
    producePair(0, 0); producePair(2, 2);
    asm volatile("s_waitcnt lgkmcnt(0)" ::: "memory");
    __builtin_amdgcn_s_barrier();                         // bar 2
    __builtin_amdgcn_sched_barrier(0);
    stageA1(6, 0); stageA1(7, 1);
    asm volatile("s_waitcnt vmcnt(0)" ::: "memory");
    __builtin_amdgcn_s_barrier();                         // bar 3
    __builtin_amdgcn_sched_barrier(0);

    int sb = 2;                                           // (2ps+2)%6
    for (int ps = 0; ps < 8; ps++) {
      // stage a1 rows 2ps+8,9 (clamped; land in just-freed slots)
      int r0 = 2 * ps + 8, r1 = 2 * ps + 9;
      stageA1(r0 > 19 ? 19 : r0, sb);
      stageA1(r1 > 19 ? 19 : r1, m6(sb + 1));
      // produce a2 rows 2ps+4,5 (a1 rows 2ps+4..2ps+7 staged+drained)
      if (2 * ps + 4 <= 17) producePair(2 * ps + 4, m6(sb + 2));
      // own-wave drains BEFORE the shared barrier (cross-wave visibility)
      asm volatile("s_waitcnt vmcnt(0) lgkmcnt(0)" ::: "memory");
      __builtin_amdgcn_s_barrier();                       // bar 4+ps
      __builtin_amdgcn_sched_barrier(0);
      sb = m6(sb + 2);
    }
  } else {
    // ------------------------- CONSUMER (conv3) -------------------------
    const int cw = wave - 4;
    const int Mh = cw >> 1, ntw = cw & 1;
    v8bf breg3[9][2];                          // tap, kb
    #pragma unroll
    for (int tap = 0; tap < 9; tap++)
      #pragma unroll
      for (int kb = 0; kb < 2; kb++)
        breg3[tap][kb] = *(const v8bf*)(B3t + (size_t)(ntw * 16 + l15) * 576
                                            + tap * 64 + kb * 32 + q * 8);
    const v4f bv3 = *(const v4f*)(b3 + ntw * 16 + q * 4);  // 4 couts/lane

    __builtin_amdgcn_s_barrier();                         // bar 1
    __builtin_amdgcn_s_barrier();                         // bar 2
    __builtin_amdgcn_s_barrier();                         // bar 3

    int sc = 0;                                           // (2ps)%6
    for (int ps = 0; ps < 8; ps++) {
      v4f acc3[2][2];                             // [rr][mt]
      #pragma unroll
      for (int rr = 0; rr < 2; rr++)
        #pragma unroll
        for (int mt = 0; mt < 2; mt++)
          acc3[rr][mt] = bv3;

      __builtin_amdgcn_s_setprio(1);
      #pragma unroll
      for (int t = 0; t < 4; t++) {
        const char* srow = a2r + m6(sc + t) * A2ROWB;
        #pragma unroll
        for (int dx = 0; dx < 3; dx++) {
          #pragma unroll
          for (int kb = 0; kb < 2; kb++) {
            v8bf af[2];
            #pragma unroll
            for (int mt = 0; mt < 2; mt++) {
              int P = Mh * 32 + mt * 16 + l15 + dx;   // 0..65
              af[mt] = *(const v8bf*)(srow + (size_t)swz(P * 8 + kb * 4 + q) * 16);
            }
            #pragma unroll
            for (int mt = 0; mt < 2; mt++) {
              if (t <= 2)                         // SWAPPED: D[cout][px]
                acc3[0][mt] = __builtin_amdgcn_mfma_f32_16x16x32_bf16(
                    breg3[t * 3 + dx][kb], af[mt], acc3[0][mt], 0, 0, 0);
              if (t >= 1)
                acc3[1][mt] = __builtin_amdgcn_mfma_f32_16x16x32_bf16(
                    breg3[(t - 1) * 3 + dx][kb], af[mt], acc3[1][mt], 0, 0, 0);
            }
          }
        }
      }
      __builtin_amdgcn_s_setprio(0);

      // lane holds px = Mh*32+mt*16+l15, couts ntw*16+q*4+(0..3): one b64
      #pragma unroll
      for (int rr = 0; rr < 2; rr++) {
        size_t rb = ((size_t)b * PADPLANE
                     + (size_t)(y0 + 2 * ps + rr + 1) * PADW + x0 + 1) * 32;
        #pragma unroll
        for (int mt = 0; mt < 2; mt++) {
          int px = Mh * 32 + mt * 16 + l15;
          unsigned int lo = pack2(fmaxf(acc3[rr][mt][0], 0.f),
                                  fmaxf(acc3[rr][mt][1], 0.f));
          unsigned int hi = pack2(fmaxf(acc3[rr][mt][2], 0.f),
                                  fmaxf(acc3[rr][mt][3], 0.f));
          *(uint2*)(act3 + rb + (size_t)px * 32 + ntw * 16 + q * 4)
              = make_uint2(lo, hi);
        }
      }
      __builtin_amdgcn_s_barrier();                       // bar 4+ps
      __builtin_amdgcn_sched_barrier(0);
      sc = m6(sc + 2);
    }
  }
}

// ---------------------------------------------------------------------------
// conv4 (32->1): LDS-staged act3 reads. ROUND-10: x split into 2 halves of
// 130 staged px (C4ROWB 8320), 4 output rows/block via 6-row staging ->
// LDS 49920 B = 3 blocks/CU (12 waves, was 8) and all 256 threads busy
// (thread = px 0..127 x row-pair 0..1). FMA/tap logic identical to the
// measured-neutral r3 form.
// ---------------------------------------------------------------------------
#define C4ROWB 8320   // 130 px * 32 ch * 2 B = 520 chunks
__global__ __launch_bounds__(256, 2) void conv4_k(
    const __bf16* __restrict__ act3, const float* __restrict__ w4t,
    const float* __restrict__ b4, const float* __restrict__ sfp,
    float* __restrict__ dout)
{
  const int tid = threadIdx.x, lane = tid & 63, wave = tid >> 6;
  const int y0 = blockIdx.x * 4, xh = blockIdx.y, b = blockIdx.z;
  const int xbase = xh * 128;
  const float b4v = b4[0], sf = sfp[0];
  const __bf16* plane = act3 + (size_t)b * PADPLANE * 32;
  __shared__ __align__(16) char smem[6 * C4ROWB];

  // stage padded rows y0..y0+5, px xbase..xbase+129 (520 chunks each)
  #pragma unroll
  for (int r = 0; r < 6; r++) {
    const char* g = (const char*)(plane + ((size_t)(y0 + r) * PADW + xbase) * 32);
    char* lrow = smem + r * C4ROWB;
    const int base = wave * 130;
    #pragma unroll
    for (int j = 0; j < 2; j++) {
      int c = base + j * 64 + lane;
      gl_lds(g + (size_t)swz(c) * 16, lrow + (base + j * 64) * 16);
    }
    if (lane < 2) {
      int c = base + 128 + lane;
      gl_lds(g + (size_t)swz(c) * 16, lrow + (base + 128) * 16);
    }
  }
  asm volatile("s_waitcnt vmcnt(0)" ::: "memory");
  __builtin_amdgcn_s_barrier();

  const int px = tid & 127, pp = tid >> 7;    // output rows y0+2pp, y0+2pp+1
  float acc0 = b4v, acc1 = b4v;
  #pragma unroll
  for (int t = 0; t < 4; t++) {
    const char* srow = smem + (2 * pp + t) * C4ROWB;
    uint4 L[12];
    #pragma unroll
    for (int j = 0; j < 12; j++) {
      int chunk = (px + (j >> 2)) * 4 + (j & 3);
      L[j] = *(const uint4*)(srow + (size_t)swz(chunk) * 16);
    }
    #pragma unroll
    for (int j = 0; j < 12; j++) {
      const int dx = j >> 2, c0 = (j & 3) * 8;
      unsigned int uu[4] = {L[j].x, L[j].y, L[j].z, L[j].w};
      float f[8];
      #pragma unroll
      for (int k = 0; k < 4; k++) {
        f[2*k]   = __builtin_bit_cast(float, uu[k] << 16);
        f[2*k+1] = __builtin_bit_cast(float, uu[k] & 0xFFFF0000u);
      }
      if (t <= 2) {
        const float* wp = w4t + (t * 3 + dx) * 32 + c0;          // uniform
        #pragma unroll
        for (int k = 0; k < 8; k++) acc0 = fmaf(wp[k], f[k], acc0);
      }
      if (t >= 1) {
        const float* wp = w4t + ((t - 1) * 3 + dx) * 32 + c0;    // uniform
        #pragma unroll
        for (int k = 0; k < 8; k++) acc1 = fmaf(wp[k], f[k], acc1);
      }
    }
  }
  size_t p0 = ((size_t)b << 16) + (size_t)(y0 + 2 * pp) * WIDTH + xbase + px;
  float vh0 = acc0 * sf, vh1 = acc1 * sf;
  dout[p0]                   = dout[524288 + p0] + vh0;          // outputs
  dout[2621440 + p0]         = vh0;                              // V_hat
  dout[p0 + WIDTH]           = dout[524288 + p0 + WIDTH] + vh1;
  dout[2621440 + p0 + WIDTH] = vh1;
}

// ---------------------------------------------------------------------------
extern "C" void kernel_launch(void* const* d_in, const int* in_sizes, int n_in,
                              void* d_out, int out_size, void* d_ws, size_t ws_size,
                              hipStream_t stream) {
  const float* inputs = (const float*)d_in[0];
  const float* H0     = (const float*)d_in[1];
  const float* C0     = (const float*)d_in[2];
  const float* c2     = (const float*)d_in[3];
  const float* sf     = (const float*)d_in[4];
  const float* w1     = (const float*)d_in[5];
  const float* b1     = (const float*)d_in[6];
  const float* w2     = (const float*)d_in[7];
  const float* b2     = (const float*)d_in[8];
  const float* w3     = (const float*)d_in[9];
  const float* b3     = (const float*)d_in[10];
  const float* w4     = (const float*)d_in[11];
  const float* b4     = (const float*)d_in[12];
  float* out = (float*)d_out;
  float* ws  = (float*)d_ws;

  float*  w1t  = ws;                               // 288 fp32
  float*  w4t  = ws + 288;                         // 288 fp32
  __bf16* B2t  = (__bf16*)(ws + 576);              // 18432 bf16
  __bf16* B3t  = (__bf16*)(ws + 9792);             // 18432 bf16
  __bf16* act1 = (__bf16*)(ws + 19008);            // 8*66564*32 bf16
  __bf16* act3 = act1 + (size_t)8 * PADPLANE * 32; // 8*66564*32 bf16

  wz_k<<<1175, 256, 0, stream>>>(w1, w2, w3, w4, w1t, B2t, B3t, w4t,
                                 act1, act3);
  prepconv1_k<<<dim3(256, 8), 256, 0, stream>>>(inputs, H0, C0, c2, sf,
                                                w1t, b1, out, act1);
  conv23_k<<<dim3(16, 4, 8), 512, 0, stream>>>(act1, B2t, b2, B3t, b3, act3);
  conv4_k<<<dim3(64, 2, 8), 256, 0, stream>>>(act3, w4t, b4, sf, out);
}